// Round 3
// baseline (873.736 us; speedup 1.0000x reference)
//
#include <hip/hip_runtime.h>
#include <math.h>

// NOTE: harness delivers ALL integer inputs as int32 ("integer -> const int*"),
// even though the reference uses int64 edge_index. Casting to long long was the
// R1/R2 crash (fused-garbage indices -> OOB atomic writes -> device fault).

// ---------------- graph build ----------------

__global__ void k_init_deg(int* __restrict__ deg, int N) {
  int i = blockIdx.x * blockDim.x + threadIdx.x;
  if (i < N) deg[i] = 1;  // self-loop contributes 1 to every node's degree
}

__global__ void k_count(const int* __restrict__ dst, int* __restrict__ deg, int E) {
  int e = blockIdx.x * blockDim.x + threadIdx.x;
  if (e < E) atomicAdd(&deg[dst[e]], 1);
}

__global__ void k_dinv(const int* __restrict__ deg, float* __restrict__ dinv, int N) {
  int i = blockIdx.x * blockDim.x + threadIdx.x;
  if (i < N) dinv[i] = rsqrtf((float)deg[i]);  // deg >= 1 always (self-loop)
}

// exclusive scan over cnt[i] = deg[i]-1 (edges per row, excluding self-loop),
// length N+1 so rowptr[N] = E falls out automatically.
__global__ void k_scan_partial(const int* __restrict__ deg, int* __restrict__ rowptr,
                               int* __restrict__ bsums, int N) {
  __shared__ int s[1024];
  int tid = threadIdx.x;
  int idx = blockIdx.x * 1024 + tid;
  int v = (idx < N) ? (deg[idx] - 1) : 0;
  s[tid] = v;
  __syncthreads();
  for (int off = 1; off < 1024; off <<= 1) {
    int add = (tid >= off) ? s[tid - off] : 0;
    __syncthreads();
    s[tid] += add;
    __syncthreads();
  }
  if (idx <= N) rowptr[idx] = s[tid] - v;  // local exclusive
  if (tid == 1023) bsums[blockIdx.x] = s[1023];
}

__global__ void k_scan_sums(int* __restrict__ bsums, int nb) {
  __shared__ int s[1024];
  int tid = threadIdx.x;
  int v = (tid < nb) ? bsums[tid] : 0;
  s[tid] = v;
  __syncthreads();
  for (int off = 1; off < 1024; off <<= 1) {
    int add = (tid >= off) ? s[tid - off] : 0;
    __syncthreads();
    s[tid] += add;
    __syncthreads();
  }
  if (tid < nb) bsums[tid] = s[tid] - v;  // exclusive
}

__global__ void k_add_offsets(int* __restrict__ rowptr, int* __restrict__ cursor,
                              const int* __restrict__ bsums, int N) {
  int idx = blockIdx.x * 1024 + threadIdx.x;
  if (idx <= N) {
    int v = rowptr[idx] + bsums[blockIdx.x];
    rowptr[idx] = v;
    if (idx < N) cursor[idx] = v;
  }
}

__global__ void k_scatter(const int* __restrict__ src, const int* __restrict__ dst,
                          const float* __restrict__ dinv, int* __restrict__ cursor,
                          int* __restrict__ col, float* __restrict__ wgt, int E) {
  int e = blockIdx.x * blockDim.x + threadIdx.x;
  if (e < E) {
    int s = src[e];
    int d = dst[e];
    int slot = atomicAdd(&cursor[d], 1);
    col[slot] = s;
    wgt[slot] = dinv[s] * dinv[d];
  }
}

// ---------------- diffusion ----------------

__global__ void k_init_acc(const float* __restrict__ x, float* __restrict__ acc,
                           const float* __restrict__ t_ptr, int total4) {
  int i = blockIdx.x * blockDim.x + threadIdx.x;
  if (i >= total4) return;
  float c0 = expf(-t_ptr[0]);
  float4 v = ((const float4*)x)[i];
  float4 o;
  o.x = c0 * v.x; o.y = c0 * v.y; o.z = c0 * v.z; o.w = c0 * v.w;
  ((float4*)acc)[i] = o;
}

// one wave per destination row; lane owns a float2 feature slice.
// h_new[r] = dinv[r]^2 * h[r] + sum_e wgt[e] * h[col[e]];  acc[r] += coeff_k * h_new[r]
__global__ __launch_bounds__(256) void k_hop(
    const int* __restrict__ rowptr, const int* __restrict__ col,
    const float* __restrict__ wgt, const float* __restrict__ dinv,
    const float* __restrict__ hprev, float* __restrict__ hnext,
    float* __restrict__ acc, const float* __restrict__ t_ptr,
    int k, int N, int write_h) {
  int wave = threadIdx.x >> 6;
  int lane = threadIdx.x & 63;
  int r = blockIdx.x * 4 + wave;
  if (r >= N) return;
  float t = t_ptr[0];
  float coeff = expf(-t);
  for (int j = 1; j <= k; ++j) coeff *= t / (float)j;

  const float2* hp = (const float2*)hprev;
  float di = dinv[r];
  float2 hs = hp[r * 64 + lane];
  float sx = di * di * hs.x, sy = di * di * hs.y;
  float ax = 0.f, ay = 0.f;
  int e = rowptr[r], end = rowptr[r + 1];
  // unroll-2: two independent accumulator chains for MLP
  for (; e + 1 < end; e += 2) {
    int s0 = col[e], s1 = col[e + 1];
    float w0 = wgt[e], w1 = wgt[e + 1];
    float2 v0 = hp[s0 * 64 + lane];
    float2 v1 = hp[s1 * 64 + lane];
    sx += w0 * v0.x; sy += w0 * v0.y;
    ax += w1 * v1.x; ay += w1 * v1.y;
  }
  if (e < end) {
    int s0 = col[e];
    float w0 = wgt[e];
    float2 v0 = hp[s0 * 64 + lane];
    sx += w0 * v0.x; sy += w0 * v0.y;
  }
  float2 sum; sum.x = sx + ax; sum.y = sy + ay;
  if (write_h) ((float2*)hnext)[r * 64 + lane] = sum;
  float2 a = ((float2*)acc)[r * 64 + lane];
  a.x += coeff * sum.x;
  a.y += coeff * sum.y;
  ((float2*)acc)[r * 64 + lane] = a;
}

// ---------------- epilogue: out = acc @ W^T + b ----------------
// Each block handles 64 of the 128 output columns (half = blockIdx&1).
// LDS: wl[o*129 + i] (o = local out col 0..63, i = 0..127), 33 KB.
//   staging: consecutive idx -> consecutive i -> consecutive banks (coalesced)
//   read: lane=o reads wl[o*129+i], bank (o+i)%32 -> 2 lanes/bank (free, m136)
// 8 rows/thread, 1 output/lane -> 8 FMAs per LDS float; all 64 lanes of a
// wave read the same acc float4 address -> broadcast, single transaction.
__global__ __launch_bounds__(256) void k_matmul(
    const float* __restrict__ acc, const float* __restrict__ W,
    const float* __restrict__ bias, float* __restrict__ out, int N) {
  __shared__ float wl[64 * 129];
  int half = blockIdx.x & 1;
  for (int idx = threadIdx.x; idx < 64 * 128; idx += 256) {
    int o = idx >> 7, i = idx & 127;
    wl[o * 129 + i] = W[(half * 64 + o) * 128 + i];
  }
  __syncthreads();
  int wave = threadIdx.x >> 6, lane = threadIdx.x & 63;
  int o = lane;
  float bval = bias[half * 64 + o];
  int nhalf = gridDim.x >> 1;

  for (int g = (blockIdx.x >> 1) * 4 + wave; g * 8 < N; g += nhalf * 4) {
    int rb = g * 8;
    const float4* A[8];
    bool valid[8];
#pragma unroll
    for (int rr = 0; rr < 8; ++rr) {
      int r = rb + rr;
      valid[rr] = (r < N);
      A[rr] = (const float4*)(acc + (size_t)(valid[rr] ? r : rb) * 128);
    }
    float s[8] = {0, 0, 0, 0, 0, 0, 0, 0};
    for (int ic = 0; ic < 32; ++ic) {
      int ib = o * 129 + ic * 4;
      float w0 = wl[ib], w1 = wl[ib + 1], w2 = wl[ib + 2], w3 = wl[ib + 3];
#pragma unroll
      for (int rr = 0; rr < 8; ++rr) {
        float4 xv = A[rr][ic];
        s[rr] += w0 * xv.x + w1 * xv.y + w2 * xv.z + w3 * xv.w;
      }
    }
#pragma unroll
    for (int rr = 0; rr < 8; ++rr) {
      if (valid[rr]) out[(size_t)(rb + rr) * 128 + half * 64 + o] = s[rr] + bval;
    }
  }
}

// ---------------- launch ----------------

extern "C" void kernel_launch(void* const* d_in, const int* in_sizes, int n_in,
                              void* d_out, int out_size, void* d_ws, size_t ws_size,
                              hipStream_t stream) {
  const float* x = (const float*)d_in[0];
  const int* ei = (const int*)d_in[1];   // int32! (harness converts integer inputs)
  const float* t = (const float*)d_in[2];
  const float* W = (const float*)d_in[3];
  const float* b = (const float*)d_in[4];
  int N = in_sizes[0] / 128;
  int E = in_sizes[1] / 2;
  const int* srcp = ei;
  const int* dstp = ei + E;
  float* out = (float*)d_out;

  char* ws = (char*)d_ws;
  size_t off = 0;
  auto alloc = [&](size_t bytes) -> void* {
    void* p = ws + off;
    off += (bytes + 255) & ~(size_t)255;
    return p;
  };
  // ws budget (~57 MB): hA + accb are the big ones; d_out doubles as the
  // second h ping-pong buffer (dead until k_matmul, which reads accb only).
  float* hA     = (float*)alloc((size_t)N * 128 * 4);
  float* accb   = (float*)alloc((size_t)N * 128 * 4);
  int*   deg    = (int*)alloc((size_t)N * 4);
  float* dinv   = (float*)alloc((size_t)N * 4);
  int*   rowptr = (int*)alloc((size_t)(N + 1) * 4);
  int*   cursor = (int*)alloc((size_t)N * 4);
  int*   bsums  = (int*)alloc(4096);
  int*   col    = (int*)alloc((size_t)E * 4);
  float* wgt    = (float*)alloc((size_t)E * 4);
  (void)ws_size;

  int nb_scan = (N + 1 + 1023) / 1024;

  k_init_deg<<<(N + 255) / 256, 256, 0, stream>>>(deg, N);
  k_count<<<(E + 255) / 256, 256, 0, stream>>>(dstp, deg, E);
  k_dinv<<<(N + 255) / 256, 256, 0, stream>>>(deg, dinv, N);
  k_scan_partial<<<nb_scan, 1024, 0, stream>>>(deg, rowptr, bsums, N);
  k_scan_sums<<<1, 1024, 0, stream>>>(bsums, nb_scan);
  k_add_offsets<<<nb_scan, 1024, 0, stream>>>(rowptr, cursor, bsums, N);
  k_scatter<<<(E + 255) / 256, 256, 0, stream>>>(srcp, dstp, dinv, cursor, col, wgt, E);
  k_init_acc<<<(N * 128 / 4 + 255) / 256, 256, 0, stream>>>(x, accb, t, N * 128 / 4);

  const float* hprev = x;
  float* bufs[2] = {hA, out};  // out serves as h ping-pong scratch until matmul
  for (int k = 1; k <= 10; ++k) {
    float* hnext = bufs[(k - 1) & 1];
    k_hop<<<(N + 3) / 4, 256, 0, stream>>>(rowptr, col, wgt, dinv, hprev, hnext,
                                           accb, t, k, N, (k < 10) ? 1 : 0);
    hprev = hnext;
  }
  k_matmul<<<1024, 256, 0, stream>>>(accb, W, b, out, N);
}